// Round 6
// baseline (905.908 us; speedup 1.0000x reference)
//
#include <hip/hip_runtime.h>
#include <hip/hip_bf16.h>
#include <math.h>

#define S_LEN 4096
#define D_MODEL 768
#define NHEAD 12
#define DH 64
#define NLAYER 2
#define DFF 3072
#define BATCH 2
#define QSTR 2304   // fused QKV row stride

typedef __attribute__((ext_vector_type(8))) __bf16 bf16x8;
typedef __attribute__((ext_vector_type(4))) float f32x4;

__device__ __forceinline__ unsigned short f2bf_bits(float f) {
  unsigned int u = __float_as_uint(f);
  unsigned int r = (u + 0x7fffu + ((u >> 16) & 1u)) >> 16;
  return (unsigned short)r;
}

__device__ __forceinline__ float bf2f(unsigned short u) {
  return __uint_as_float(((unsigned int)u) << 16);
}

__device__ __forceinline__ unsigned int cvtpk_bf16(float lo, float hi) {
  unsigned int d;
  asm("v_cvt_pk_bf16_f32 %0, %1, %2" : "=v"(d) : "v"(lo), "v"(hi));
  return d;
}

// tanh-gelu with cheap tanh via one __expf (clamped to avoid inf/inf)
__device__ __forceinline__ float gelu_fast(float x) {
  float u = 0.7978845608028654f * (x + 0.044715f * x * x * x);
  float t2 = fminf(fmaxf(2.f * u, -18.f), 18.f);
  float e = __expf(t2);
  return 0.5f * x * (1.f + (e - 1.f) / (e + 1.f));
}

#define ASYNC_COPY16(gsrc, ldst)                                       \
  __builtin_amdgcn_global_load_lds(                                    \
      (const __attribute__((address_space(1))) void*)(gsrc),           \
      (__attribute__((address_space(3))) void*)(ldst), 16, 0, 0)

#define MFMA_BF16(a, b, c) __builtin_amdgcn_mfma_f32_16x16x32_bf16(a, b, c, 0, 0, 0)

// ---------------------------------------------------------------------------
// block-wide reductions (256 threads = 4 waves of 64)
// ---------------------------------------------------------------------------
__device__ __forceinline__ float blk_sum256(float v, float* lds) {
#pragma unroll
  for (int off = 32; off > 0; off >>= 1) v += __shfl_down(v, off, 64);
  __syncthreads();
  if ((threadIdx.x & 63) == 0) lds[threadIdx.x >> 6] = v;
  __syncthreads();
  return lds[0] + lds[1] + lds[2] + lds[3];
}

// ---------------------------------------------------------------------------
// weight transpose + fp32->bf16 convert: W[K][N] f32 -> Wt[N][K] bf16
// ---------------------------------------------------------------------------
__global__ __launch_bounds__(256) void wconv_kernel(
    const float* __restrict__ Wq, const float* __restrict__ Wk,
    const float* __restrict__ Wv, const float* __restrict__ Wo,
    const float* __restrict__ Wf1, const float* __restrict__ Wf2,
    unsigned short* __restrict__ Wbf) {
  int id = blockIdx.x;
  const float* src;
  unsigned short* dst;
  int K, N, t;
  if (id < 4608) {
    int m = id / 576;
    t = id % 576;
    int layer = m >> 2, which = m & 3;
    const float* s = (which == 0) ? Wq : (which == 1) ? Wk : (which == 2) ? Wv : Wo;
    src = s + (size_t)layer * 589824;
    dst = Wbf + (size_t)layer * 7077888 + (size_t)which * 589824;
    K = 768; N = 768;
  } else if (id < 9216) {
    int j = id - 4608;
    int layer = j / 2304;
    t = j % 2304;
    src = Wf1 + (size_t)layer * 2359296;
    dst = Wbf + (size_t)layer * 7077888 + 2359296;
    K = 768; N = 3072;
  } else {
    int j = id - 9216;
    int layer = j / 2304;
    t = j % 2304;
    src = Wf2 + (size_t)layer * 2359296;
    dst = Wbf + (size_t)layer * 7077888 + 4718592;
    K = 3072; N = 768;
  }
  int tiles_n = N >> 5;
  int tk = t / tiles_n, tn = t % tiles_n;
  __shared__ float tile[32][33];
  int c = threadIdx.x & 31, r0 = threadIdx.x >> 5;
#pragma unroll
  for (int p = 0; p < 4; ++p) {
    int r = r0 + p * 8;
    tile[r][c] = src[(size_t)(tk * 32 + r) * N + tn * 32 + c];
  }
  __syncthreads();
#pragma unroll
  for (int p = 0; p < 4; ++p) {
    int r = r0 + p * 8;
    dst[(size_t)(tn * 32 + r) * K + tk * 32 + c] = f2bf_bits(tile[c][r]);
  }
}

// ---------------------------------------------------------------------------
// embedding gather + LayerNorm; writes fp32 X and bf16 Xb
// ---------------------------------------------------------------------------
__global__ __launch_bounds__(256) void embed_ln_kernel(
    const int* __restrict__ ids, const float* __restrict__ wemb,
    const float* __restrict__ pemb, const float* __restrict__ g,
    const float* __restrict__ b, float* __restrict__ X,
    unsigned short* __restrict__ Xb) {
  int row = blockIdx.x;
  int s = row % S_LEN;
  int id = ids[row];
  const float* we = wemb + (size_t)id * D_MODEL;
  const float* pe = pemb + (size_t)s * D_MODEL;
  int t = threadIdx.x;
  __shared__ float lds[4];
  float v0 = we[t] + pe[t];
  float v1 = we[t + 256] + pe[t + 256];
  float v2 = we[t + 512] + pe[t + 512];
  float mean = blk_sum256(v0 + v1 + v2, lds) * (1.f / 768.f);
  float d0 = v0 - mean, d1 = v1 - mean, d2 = v2 - mean;
  float var = blk_sum256(d0 * d0 + d1 * d1 + d2 * d2, lds) * (1.f / 768.f);
  float rs = rsqrtf(var + 1e-5f);
  float o0 = d0 * rs * g[t] + b[t];
  float o1 = d1 * rs * g[t + 256] + b[t + 256];
  float o2 = d2 * rs * g[t + 512] + b[t + 512];
  float* xp = X + (size_t)row * D_MODEL;
  xp[t] = o0; xp[t + 256] = o1; xp[t + 512] = o2;
  unsigned short* xb = Xb + (size_t)row * D_MODEL;
  xb[t] = f2bf_bits(o0); xb[t + 256] = f2bf_bits(o1); xb[t + 512] = f2bf_bits(o2);
}

// ---------------------------------------------------------------------------
// LayerNorm: X = LN(T) * g + b ; writes fp32 X and bf16 Xb
// ---------------------------------------------------------------------------
__global__ __launch_bounds__(256) void ln_kernel(
    const float* __restrict__ T, const float* __restrict__ g,
    const float* __restrict__ b, float* __restrict__ X,
    unsigned short* __restrict__ Xb) {
  int row = blockIdx.x;
  const float* tp = T + (size_t)row * D_MODEL;
  int t = threadIdx.x;
  __shared__ float lds[4];
  float v0 = tp[t], v1 = tp[t + 256], v2 = tp[t + 512];
  float mean = blk_sum256(v0 + v1 + v2, lds) * (1.f / 768.f);
  float d0 = v0 - mean, d1 = v1 - mean, d2 = v2 - mean;
  float var = blk_sum256(d0 * d0 + d1 * d1 + d2 * d2, lds) * (1.f / 768.f);
  float rs = rsqrtf(var + 1e-5f);
  float o0 = d0 * rs * g[t] + b[t];
  float o1 = d1 * rs * g[t + 256] + b[t + 256];
  float o2 = d2 * rs * g[t + 512] + b[t + 512];
  float* xp = X + (size_t)row * D_MODEL;
  xp[t] = o0; xp[t + 256] = o1; xp[t + 512] = o2;
  unsigned short* xb = Xb + (size_t)row * D_MODEL;
  xb[t] = f2bf_bits(o0); xb[t + 256] = f2bf_bits(o1); xb[t + 512] = f2bf_bits(o2);
}

// ---------------------------------------------------------------------------
// 8-phase 256x256 MFMA GEMM (m201 template, plain HIP).
// BK=64, 512 threads = 8 waves (2M x 4N), per-wave 128x64 output,
// 128 KB LDS (2 dbuf x (A 32KB + B 32KB)). Per K-tile: 4 phases of
// {ds-reads | 2-4 stage gloads -> barrier -> lgkmcnt(0) -> setprio(1) ->
//  16 MFMA -> setprio(0) -> barrier}; group-end vmcnt drain is of loads
// issued >=2.5 phases earlier (no stall). Wave-half-aligned staging:
// each wave stages 4KB of A-half(wm) and 4KB of B-half(wn>>1).
// XOR chunk swizzle (8 slots) on both staging source and ds_read.
// MODE 1: out bf16, +bias0, gelu        (FFN1)
// MODE 4: out bf16 stride N, 3 biases, cols<768 scaled 1/8 (QKV)
// ---------------------------------------------------------------------------
template <int MODE>
__global__ __launch_bounds__(512, 2) void gemm8p(
    const unsigned short* __restrict__ A, const unsigned short* __restrict__ Bt,
    const float* __restrict__ bias0, const float* __restrict__ bias1,
    const float* __restrict__ bias2, unsigned short* __restrict__ Cout,
    int M, int N, int K) {
  __shared__ unsigned short Abuf[2][256 * 64];   // 64 KB
  __shared__ unsigned short Bbuf[2][256 * 64];   // 64 KB
  const int tid = threadIdx.x;
  const int lane = tid & 63, w = tid >> 6;
  const int wm = w >> 2, wn = w & 3;
  const int cl = lane & 15, kgrp = lane >> 4;

  // XCD-aware bijective block swizzle (nwg % 8 == 0)
  const int nbx = gridDim.x;
  const int nwg = nbx * gridDim.y;
  const int orig = blockIdx.y * nbx + blockIdx.x;
  const int wgid = (orig & 7) * (nwg >> 3) + (orig >> 3);
  const int m0 = (wgid / nbx) * 256, n0 = (wgid % nbx) * 256;

  f32x4 acc[8][4];
#pragma unroll
  for (int i = 0; i < 8; ++i)
#pragma unroll
    for (int j = 0; j < 4; ++j) acc[i][j] = (f32x4){0.f, 0.f, 0.f, 0.f};

  // ---- staging addresses (per wave: 4 A-instr + 4 B-instr per K-tile) ----
  // instr j covers 8 rows x 64 elem (1KB). lane l -> local row l>>3, chunk l&7.
  // source chunk pre-permuted: (l&7) ^ (l>>3); LDS dest linear.
  const int lrow = lane >> 3, lch = (lane & 7) ^ lrow;
  const unsigned short* gA[4];
  const unsigned short* gB[4];
  int dstA[4], dstB[4];
#pragma unroll
  for (int j = 0; j < 4; ++j) {
    int arl = wm * 128 + wn * 32 + j * 8;                      // A local row base
    gA[j] = A + (size_t)(m0 + arl + lrow) * K + lch * 8;
    dstA[j] = arl * 64;
    int brl = (wn >> 1) * 128 + (wm * 2 + (wn & 1)) * 32 + j * 8;
    gB[j] = Bt + (size_t)(n0 + brl + lrow) * K + lch * 8;
    dstB[j] = brl * 64;
  }

#define STAGE_A(pp)                                                   \
  {                                                                   \
    _Pragma("unroll") for (int j = 0; j < 4; ++j) {                   \
      ASYNC_COPY16(gA[j], &Abuf[pp][dstA[j]]);                        \
      gA[j] += 64;                                                    \
    }                                                                 \
  }
#define STAGE_B(pp)                                                   \
  {                                                                   \
    _Pragma("unroll") for (int j = 0; j < 4; ++j) {                   \
      ASYNC_COPY16(gB[j], &Bbuf[pp][dstB[j]]);                        \
      gB[j] += 64;                                                    \
    }                                                                 \
  }

  const int nk = K >> 6;
  // prologue: stage tile 0 into buf 0
  STAGE_A(0);
  STAGE_B(0);
  asm volatile("s_waitcnt vmcnt(0)" ::: "memory");
  __builtin_amdgcn_s_barrier();
  __builtin_amdgcn_sched_barrier(0);

  bf16x8 a[4][2], b0[2][2], b1[2][2];
  for (int t = 0; t < nk; ++t) {
    const int p = t & 1;
    const bool pre = (t + 1 < nk);

    // ===== phase 0: read A-lo(8) + B-lo(4); stage next A =====
#pragma unroll
    for (int i = 0; i < 4; ++i)
#pragma unroll
      for (int ks = 0; ks < 2; ++ks) {
        int row = wm * 128 + i * 16 + cl;
        a[i][ks] = *(const bf16x8*)(&Abuf[p][row * 64 + ((((ks << 2) | kgrp) ^ (cl & 7)) << 3)]);
      }
#pragma unroll
    for (int n = 0; n < 2; ++n)
#pragma unroll
      for (int ks = 0; ks < 2; ++ks) {
        int row = wn * 64 + n * 16 + cl;
        b0[n][ks] = *(const bf16x8*)(&Bbuf[p][row * 64 + ((((ks << 2) | kgrp) ^ (cl & 7)) << 3)]);
      }
    if (pre) STAGE_A(p ^ 1);
    __builtin_amdgcn_s_barrier();
    asm volatile("s_waitcnt lgkmcnt(0)" ::: "memory");
    __builtin_amdgcn_sched_barrier(0);
    __builtin_amdgcn_s_setprio(1);
#pragma unroll
    for (int i = 0; i < 4; ++i)
#pragma unroll
      for (int n = 0; n < 2; ++n)
#pragma unroll
        for (int ks = 0; ks < 2; ++ks)
          acc[i][n] = MFMA_BF16(a[i][ks], b0[n][ks], acc[i][n]);
    __builtin_amdgcn_s_setprio(0);
    __builtin_amdgcn_s_barrier();

    // ===== phase 1: read B-hi(4); stage next B =====
#pragma unroll
    for (int n = 0; n < 2; ++n)
#pragma unroll
      for (int ks = 0; ks < 2; ++ks) {
        int row = wn * 64 + 32 + n * 16 + cl;
        b1[n][ks] = *(const bf16x8*)(&Bbuf[p][row * 64 + ((((ks << 2) | kgrp) ^ (cl & 7)) << 3)]);
      }
    if (pre) STAGE_B(p ^ 1);
    __builtin_amdgcn_s_barrier();
    asm volatile("s_waitcnt lgkmcnt(0)" ::: "memory");
    __builtin_amdgcn_sched_barrier(0);
    __builtin_amdgcn_s_setprio(1);
#pragma unroll
    for (int i = 0; i < 4; ++i)
#pragma unroll
      for (int n = 0; n < 2; ++n)
#pragma unroll
        for (int ks = 0; ks < 2; ++ks)
          acc[i][2 + n] = MFMA_BF16(a[i][ks], b1[n][ks], acc[i][2 + n]);
    __builtin_amdgcn_s_setprio(0);
    __builtin_amdgcn_s_barrier();

    // ===== phase 2: read A-hi(8) =====
#pragma unroll
    for (int i = 0; i < 4; ++i)
#pragma unroll
      for (int ks = 0; ks < 2; ++ks) {
        int row = wm * 128 + 64 + i * 16 + cl;
        a[i][ks] = *(const bf16x8*)(&Abuf[p][row * 64 + ((((ks << 2) | kgrp) ^ (cl & 7)) << 3)]);
      }
    __builtin_amdgcn_s_barrier();
    asm volatile("s_waitcnt lgkmcnt(0)" ::: "memory");
    __builtin_amdgcn_sched_barrier(0);
    __builtin_amdgcn_s_setprio(1);
#pragma unroll
    for (int i = 0; i < 4; ++i)
#pragma unroll
      for (int n = 0; n < 2; ++n)
#pragma unroll
        for (int ks = 0; ks < 2; ++ks)
          acc[4 + i][n] = MFMA_BF16(a[i][ks], b0[n][ks], acc[4 + i][n]);
    __builtin_amdgcn_s_setprio(0);
    __builtin_amdgcn_s_barrier();

    // ===== phase 3: no reads; MFMA q3; group-end drain =====
    __builtin_amdgcn_s_setprio(1);
#pragma unroll
    for (int i = 0; i < 4; ++i)
#pragma unroll
      for (int n = 0; n < 2; ++n)
#pragma unroll
        for (int ks = 0; ks < 2; ++ks)
          acc[4 + i][2 + n] = MFMA_BF16(a[i][ks], b1[n][ks], acc[4 + i][2 + n]);
    __builtin_amdgcn_s_setprio(0);
    if (pre) asm volatile("s_waitcnt vmcnt(0)" ::: "memory");
    __builtin_amdgcn_s_barrier();
    __builtin_amdgcn_sched_barrier(0);
  }
#undef STAGE_A
#undef STAGE_B

  // ---- epilogue ----
#pragma unroll
  for (int mi = 0; mi < 8; ++mi) {
#pragma unroll
    for (int ni = 0; ni < 4; ++ni) {
      int gr0 = m0 + wm * 128 + mi * 16 + kgrp * 4;
      int gc = n0 + wn * 64 + ni * 16 + cl;
      float bsv;
      if (MODE == 4)
        bsv = (gc < 768) ? bias0[gc] : (gc < 1536) ? bias1[gc - 768] : bias2[gc - 1536];
      else
        bsv = bias0[gc];
#pragma unroll
      for (int r = 0; r < 4; ++r) {
        float v = acc[mi][ni][r] + bsv;
        if (MODE == 1) v = gelu_fast(v);
        if (MODE == 4 && gc < 768) v *= 0.125f;
        Cout[(size_t)(gr0 + r) * N + gc] = f2bf_bits(v);
      }
    }
  }
}

// ---------------------------------------------------------------------------
// 128x128 bf16 MFMA GEMM (kept for N=768 shapes). MODE 2: f32 out,+bias,+Res.
// ---------------------------------------------------------------------------
template <int MODE>
__global__ __launch_bounds__(256) void gemm_bf16(
    const unsigned short* __restrict__ A, const unsigned short* __restrict__ Bt,
    const float* __restrict__ bias0, const float* __restrict__ Res,
    void* __restrict__ Cout, int M, int N, int K) {
  __shared__ unsigned short Abuf[3][128 * 32];
  __shared__ unsigned short Bbuf[3][128 * 32];
  const int tid = threadIdx.x;
  const int lane = tid & 63, w = tid >> 6;
  const int wm = w >> 1, wn = w & 1;

  const int nbx = gridDim.x;
  const int nwg = nbx * gridDim.y;
  const int orig = blockIdx.y * nbx + blockIdx.x;
  const int wgid = (orig & 7) * (nwg >> 3) + (orig >> 3);
  const int m0 = (wgid / nbx) * 128, n0 = (wgid % nbx) * 128;

  f32x4 acc[4][4];
#pragma unroll
  for (int i = 0; i < 4; ++i)
#pragma unroll
    for (int j = 0; j < 4; ++j) acc[i][j] = (f32x4){0.f, 0.f, 0.f, 0.f};

  const int s0 = w * 64 + lane, s1 = s0 + 256;
  const int r0 = s0 >> 2, c0 = (s0 & 3) ^ (r0 & 3);
  const int r1 = s1 >> 2, c1 = (s1 & 3) ^ (r1 & 3);
  const unsigned short* gA0 = A + (size_t)(m0 + r0) * K + c0 * 8;
  const unsigned short* gA1 = A + (size_t)(m0 + r1) * K + c1 * 8;
  const unsigned short* gB0 = Bt + (size_t)(n0 + r0) * K + c0 * 8;
  const unsigned short* gB1 = Bt + (size_t)(n0 + r1) * K + c1 * 8;
  const int dA0 = (w * 64) * 8, dA1 = (256 + w * 64) * 8;

  const int frow = lane & 15, kgrp = lane >> 4;
  int aoff[4], boff[4];
#pragma unroll
  for (int i = 0; i < 4; ++i) {
    int ra = wm * 64 + i * 16 + frow;
    int rb = wn * 64 + i * 16 + frow;
    aoff[i] = ra * 32 + ((kgrp ^ (ra & 3)) * 8);
    boff[i] = rb * 32 + ((kgrp ^ (rb & 3)) * 8);
  }

#define STAGE(bsel)                                                       \
  {                                                                       \
    ASYNC_COPY16(gA0, &Abuf[bsel][dA0]);                                  \
    ASYNC_COPY16(gA1, &Abuf[bsel][dA1]);                                  \
    ASYNC_COPY16(gB0, &Bbuf[bsel][dA0]);                                  \
    ASYNC_COPY16(gB1, &Bbuf[bsel][dA1]);                                  \
    gA0 += 32; gA1 += 32; gB0 += 32; gB1 += 32;                           \
  }

  const int nk = K >> 5;
  STAGE(0);
  if (nk > 1) STAGE(1);
  asm volatile("s_waitcnt vmcnt(4)" ::: "memory");
  __builtin_amdgcn_s_barrier();
  __builtin_amdgcn_sched_barrier(0);

  int cur = 0;
  for (int kt = 0; kt < nk; ++kt) {
    if (kt + 2 < nk) {
      int nxt = cur + 2;
      if (nxt >= 3) nxt -= 3;
      STAGE(nxt);
    }
    bf16x8 av[4], bv[4];
#pragma unroll
    for (int i = 0; i < 4; ++i) av[i] = *(const bf16x8*)(&Abuf[cur][aoff[i]]);
#pragma unroll
    for (int j = 0; j < 4; ++j) bv[j] = *(const bf16x8*)(&Bbuf[cur][boff[j]]);
#pragma unroll
    for (int i = 0; i < 4; ++i)
#pragma unroll
      for (int j = 0; j < 4; ++j)
        acc[i][j] = MFMA_BF16(av[i], bv[j], acc[i][j]);
    if (kt + 1 < nk) {
      if (kt + 2 < nk)
        asm volatile("s_waitcnt vmcnt(4)" ::: "memory");
      else
        asm volatile("s_waitcnt vmcnt(0)" ::: "memory");
      __builtin_amdgcn_s_barrier();
      __builtin_amdgcn_sched_barrier(0);
    }
    cur = (cur == 2) ? 0 : cur + 1;
  }
#undef STAGE

#pragma unroll
  for (int i = 0; i < 4; ++i) {
#pragma unroll
    for (int j = 0; j < 4; ++j) {
      int grb = m0 + wm * 64 + i * 16 + (lane >> 4) * 4;
      int gc = n0 + wn * 64 + j * 16 + (lane & 15);
      float bsv = bias0[gc];
#pragma unroll
      for (int r = 0; r < 4; ++r) {
        int gr = grb + r;
        float v = acc[i][j][r] + bsv;
        if (MODE == 2) v += Res[(size_t)gr * N + gc];
        ((float*)Cout)[(size_t)gr * N + gc] = v;
      }
    }
  }
}

// ---------------------------------------------------------------------------
// V transpose per (b,h): QKV V-cols -> Vt[(b*12+h)*64 + d][4096] bf16
// ---------------------------------------------------------------------------
__global__ __launch_bounds__(256) void vtrans_kernel(
    const unsigned short* __restrict__ Vsrc, unsigned short* __restrict__ Vt) {
  int kb = blockIdx.x, h = blockIdx.y, b = blockIdx.z;
  int k0 = kb * 64;
  const size_t bs = (size_t)b * S_LEN;
  const size_t bh = (size_t)(b * NHEAD + h);
  __shared__ unsigned short tile[64][72];
  int tid = threadIdx.x;
#pragma unroll
  for (int p = 0; p < 2; ++p) {
    int idx = p * 256 + tid;
    int key = idx >> 3, ch = idx & 7;
    bf16x8 v = *(const bf16x8*)(Vsrc + (bs + k0 + key) * QSTR + h * DH + ch * 8);
    *(bf16x8*)&tile[key][ch * 8] = v;
  }
  __syncthreads();
#pragma unroll
  for (int p = 0; p < 2; ++p) {
    int idx = p * 256 + tid;
    int d = idx >> 3, kc = idx & 7;
    unsigned int w0 = tile[kc * 8 + 0][d] | ((unsigned int)tile[kc * 8 + 1][d] << 16);
    unsigned int w1 = tile[kc * 8 + 2][d] | ((unsigned int)tile[kc * 8 + 3][d] << 16);
    unsigned int w2 = tile[kc * 8 + 4][d] | ((unsigned int)tile[kc * 8 + 5][d] << 16);
    unsigned int w3 = tile[kc * 8 + 6][d] | ((unsigned int)tile[kc * 8 + 7][d] << 16);
    uint4 out = make_uint4(w0, w1, w2, w3);
    *(uint4*)(Vt + (bh * 64 + d) * S_LEN + k0 + kc * 8) = out;
  }
}

// ---------------------------------------------------------------------------
// MFMA band attention + fused global-row-0 path.
// grid (17, H=12, B=2), 512 threads = 8 waves.
// ---------------------------------------------------------------------------
__global__ __launch_bounds__(512) void band_attn_kernel(
    const unsigned short* __restrict__ Qg, const unsigned short* __restrict__ Kgb,
    const unsigned short* __restrict__ Vgb, const unsigned short* __restrict__ Vt,
    const int* __restrict__ att, unsigned short* __restrict__ Aout) {
  const int c = blockIdx.x, h = blockIdx.y, b = blockIdx.z;
  const int tid = threadIdx.x;
  const int lane = tid & 63, wq = tid >> 6;
  const int g = lane >> 4, cl = lane & 15;
  const size_t bs = (size_t)b * S_LEN;
  const size_t bh = (size_t)(b * NHEAD + h);

  __shared__ __align__(16) char smem[18944];

  if (c == 16) {
    float* sc = (float*)smem;
    float* q0 = sc + S_LEN;
    float* red = q0 + 64;
    float* part = red + 8;
    if (tid < 64) q0[tid] = bf2f(Qg[bs * QSTR + h * DH + tid]);
    __syncthreads();
    float lmax = -1e30f;
    for (int s = tid; s < S_LEN; s += 512) {
      const unsigned short* kp = Kgb + (bs + s) * QSTR + h * DH;
      float acc = 0.f;
#pragma unroll
      for (int cc = 0; cc < 8; ++cc) {
        uint4 u = *(const uint4*)(kp + cc * 8);
        const unsigned int* uu = (const unsigned int*)&u;
#pragma unroll
        for (int w2 = 0; w2 < 4; ++w2) {
          unsigned int x = uu[w2];
          acc += q0[cc * 8 + w2 * 2] * __uint_as_float(x << 16);
          acc += q0[cc * 8 + w2 * 2 + 1] * __uint_as_float(x & 0xffff0000u);
        }
      }
      acc = (att[b * S_LEN + s] > 0) ? acc : -1e9f;
      sc[s] = acc;
      lmax = fmaxf(lmax, acc);
    }
#pragma unroll
    for (int off = 32; off > 0; off >>= 1) lmax = fmaxf(lmax, __shfl_down(lmax, off, 64));
    __syncthreads();
    if (lane == 0) red[wq] = lmax;
    __syncthreads();
    float M = red[0];
#pragma unroll
    for (int i = 1; i < 8; ++i) M = fmaxf(M, red[i]);
    float lsum = 0.f;
    for (int s = tid; s < S_LEN; s += 512) {
      float p = __expf(sc[s] - M);
      sc[s] = p;
      lsum += p;
    }
#pragma unroll
    for (int off = 32; off > 0; off >>= 1) lsum += __shfl_down(lsum, off, 64);
    __syncthreads();
    if (lane == 0) red[wq] = lsum;
    __syncthreads();
    float L = red[0];
#pragma unroll
    for (int i = 1; i < 8; ++i) L += red[i];
    int d = tid & 63, chunk = tid >> 6;
    float acc2 = 0.f;
    for (int s = chunk * 512; s < (chunk + 1) * 512; ++s)
      acc2 += sc[s] * bf2f(Vgb[(bs + s) * QSTR + h * DH + d]);
    part[chunk * 64 + d] = acc2;
    __syncthreads();
    if (tid < 64) {
      float v = 0.f;
#pragma unroll
      for (int i = 0; i < 8; ++i) v += part[i * 64 + tid];
      Aout[bs * D_MODEL + h * DH + tid] = f2bf_bits(v / L);
    }
    return;
  }

  unsigned short* Klds = (unsigned short*)smem;
  unsigned short* Vlds = Klds + 64 * 64;
  float* kmask = (float*)(Vlds + 64 * 64);

  bf16x8 qf[2][2];
#pragma unroll
  for (int qt = 0; qt < 2; ++qt)
#pragma unroll
    for (int ks = 0; ks < 2; ++ks)
      qf[qt][ks] = *(const bf16x8*)(Qg + (bs + c * 256 + wq * 32 + qt * 16 + cl) * QSTR +
                                    h * DH + ks * 32 + g * 8);

  float mrun[2], lrun[2];
  f32x4 oacc[2][4];
#pragma unroll
  for (int qt = 0; qt < 2; ++qt) {
    float sg = 0.f;
#pragma unroll
    for (int ks = 0; ks < 2; ++ks) {
      bf16x8 k0 = *(const bf16x8*)(Kgb + bs * QSTR + h * DH + ks * 32 + g * 8);
#pragma unroll
      for (int j = 0; j < 8; ++j) sg += (float)qf[qt][ks][j] * (float)k0[j];
    }
    sg += __shfl_xor(sg, 16, 64);
    sg += __shfl_xor(sg, 32, 64);
    mrun[qt] = sg;
    lrun[qt] = 1.f;
  }
#pragma unroll
  for (int dt = 0; dt < 4; ++dt) {
    float v0d = bf2f(Vgb[bs * QSTR + h * DH + dt * 16 + cl]);
    f32x4 vv = {v0d, v0d, v0d, v0d};
    oacc[0][dt] = vv;
    oacc[1][dt] = vv;
  }

  const int jlo = wq * 32, jhi = wq * 32 + 543;

  for (int t = 0; t < 12; ++t) {
    int kabs0 = c * 256 - 256 + t * 64;
    if (kabs0 < 0 || kabs0 >= S_LEN) continue;
    __syncthreads();
    {
      int key = tid >> 3, ch = tid & 7;
      bf16x8 kv = *(const bf16x8*)(Kgb + (bs + kabs0 + key) * QSTR + h * DH + ch * 8);
      *(bf16x8*)(Klds + key * 64 + ((ch ^ (key & 7)) * 8)) = kv;
      bf16x8 vv = *(const bf16x8*)(Vt + (bh * 64 + key) * S_LEN + kabs0 + ch * 8);
      *(bf16x8*)(Vlds + key * 64 + ((ch ^ (key & 7)) * 8)) = vv;
      if (tid < 64) {
        int ka = kabs0 + tid;
        kmask[tid] = (ka >= 1 && att[b * S_LEN + ka] > 0) ? 0.f : -1e9f;
      }
    }
    __syncthreads();
    if (t * 64 + 63 < jlo || t * 64 > jhi) continue;

    f32x4 accs[4][2];
#pragma unroll
    for (int kt = 0; kt < 4; ++kt) {
      accs[kt][0] = (f32x4){0.f, 0.f, 0.f, 0.f};
      accs[kt][1] = (f32x4){0.f, 0.f, 0.f, 0.f};
    }
#pragma unroll
    for (int ks = 0; ks < 2; ++ks) {
      bf16x8 kf[4];
#pragma unroll
      for (int kt = 0; kt < 4; ++kt) {
        int key = kt * 16 + cl;
        kf[kt] = *(const bf16x8*)(Klds + key * 64 + (((ks * 4 + g) ^ (key & 7)) * 8));
      }
#pragma unroll
      for (int kt = 0; kt < 4; ++kt) {
        accs[kt][0] = MFMA_BF16(kf[kt], qf[0][ks], accs[kt][0]);
        accs[kt][1] = MFMA_BF16(kf[kt], qf[1][ks], accs[kt][1]);
      }
    }

#pragma unroll
    for (int qt = 0; qt < 2; ++qt) {
      int iq = wq * 32 + qt * 16 + cl;
      int relbase = t * 64 - iq;
      float pvv[4][4];
      float tmax = -1e30f;
#pragma unroll
      for (int kt = 0; kt < 4; ++kt)
#pragma unroll
        for (int r = 0; r < 4; ++r) {
          int key = kt * 16 + g * 4 + r;
          int rel = relbase + key;
          float x = accs[kt][qt][r] + kmask[key];
          x = (rel >= 0 && rel <= 512) ? x : -1e9f;
          pvv[kt][r] = x;
          tmax = fmaxf(tmax, x);
        }
      tmax = fmaxf(tmax, __shfl_xor(tmax, 16, 64));
      tmax = fmaxf(tmax, __shfl_xor(tmax, 32, 64));
      float mnew = fmaxf(mrun[qt], tmax);
      float scale = __expf(mrun[qt] - mnew);
      mrun[qt] = mnew;
      float psum = 0.f;
#pragma unroll
      for (int kt = 0; kt < 4; ++kt)
#pragma unroll
        for (int r = 0; r < 4; ++r) {
          float p = __expf(pvv[kt][r] - mnew);
          pvv[kt][r] = p;
          psum += p;
        }
      psum += __shfl_xor(psum, 16, 64);
      psum += __shfl_xor(psum, 32, 64);
      lrun[qt] = lrun[qt] * scale + psum;
      float scr[4];
#pragma unroll
      for (int r = 0; r < 4; ++r) scr[r] = __shfl(scale, g * 4 + r, 64);
#pragma unroll
      for (int dt = 0; dt < 4; ++dt) {
        oacc[qt][dt][0] *= scr[0];
        oacc[qt][dt][1] *= scr[1];
        oacc[qt][dt][2] *= scr[2];
        oacc[qt][dt][3] *= scr[3];
      }
#pragma unroll
      for (int ks = 0; ks < 2; ++ks) {
        unsigned int E0D0 = cvtpk_bf16(pvv[ks * 2][0], pvv[ks * 2][1]);
        unsigned int E0D1 = cvtpk_bf16(pvv[ks * 2][2], pvv[ks * 2][3]);
        unsigned int E1D0 = cvtpk_bf16(pvv[ks * 2 + 1][0], pvv[ks * 2 + 1][1]);
        unsigned int E1D1 = cvtpk_bf16(pvv[ks * 2 + 1][2], pvv[ks * 2 + 1][3]);
        int src0 = ((lane >> 4) & 1) * 32 + cl;
        int src1 = src0 + 16;
        unsigned int a0 = (unsigned int)__shfl((int)E0D0, src0, 64);
        unsigned int a1 = (unsigned int)__shfl((int)E0D1, src0, 64);
        unsigned int a2 = (unsigned int)__shfl((int)E0D0, src1, 64);
        unsigned int a3 = (unsigned int)__shfl((int)E0D1, src1, 64);
        unsigned int b0 = (unsigned int)__shfl((int)E1D0, src0, 64);
        unsigned int b1 = (unsigned int)__shfl((int)E1D1, src0, 64);
        unsigned int b2 = (unsigned int)__shfl((int)E1D0, src1, 64);
        unsigned int b3 = (unsigned int)__shfl((int)E1D1, src1, 64);
        bool hi = lane >= 32;
        union { unsigned int u[4]; bf16x8 v; } af;
        af.u[0] = hi ? b0 : a0;
        af.u[1] = hi ? b1 : a1;
        af.u[2] = hi ? b2 : a2;
        af.u[3] = hi ? b3 : a3;
#pragma unroll
        for (int dt = 0; dt < 4; ++dt) {
          int d = dt * 16 + cl;
          bf16x8 vf = *(const bf16x8*)(Vlds + d * 64 + (((ks * 4 + g) ^ (d & 7)) * 8));
          oacc[qt][dt] = MFMA_BF16(af.v, vf, oacc[qt][dt]);
        }
      }
    }
  }

#pragma unroll
  for (int qt = 0; qt < 2; ++qt) {
    float lr[4];
#pragma unroll
    for (int r = 0; r < 4; ++r) lr[r] = 1.f / __shfl(lrun[qt], g * 4 + r, 64);
#pragma unroll
    for (int dt = 0; dt < 4; ++dt)
#pragma unroll
      for (int r = 0; r < 4; ++r) {
        int row = c * 256 + wq * 32 + qt * 16 + g * 4 + r;
        if (row != 0)
          Aout[(bs + row) * D_MODEL + h * DH + dt * 16 + cl] =
              f2bf_bits(oacc[qt][dt][r] * lr[r]);
      }
  }
}

// ---------------------------------------------------------------------------
// masked mean-pool, two stages
// ---------------------------------------------------------------------------
__global__ __launch_bounds__(256) void pool1_kernel(
    const float* __restrict__ X, const int* __restrict__ att,
    float* __restrict__ ppart) {
  int sb = blockIdx.x, b = blockIdx.y, t = threadIdx.x;
  float a0 = 0.f, a1 = 0.f, a2 = 0.f;
  for (int s = sb * 256; s < sb * 256 + 256; ++s) {
    float a = (float)att[b * S_LEN + s];
    const float* xp = X + ((size_t)b * S_LEN + s) * D_MODEL;
    a0 += xp[t] * a; a1 += xp[t + 256] * a; a2 += xp[t + 512] * a;
  }
  float* pp = ppart + ((size_t)b * 16 + sb) * D_MODEL;
  pp[t] = a0; pp[t + 256] = a1; pp[t + 512] = a2;
}

__global__ __launch_bounds__(256) void pool2_kernel(
    const float* __restrict__ ppart, const int* __restrict__ att,
    float* __restrict__ pooled) {
  int b = blockIdx.x, t = threadIdx.x;
  float a0 = 0.f, a1 = 0.f, a2 = 0.f;
  for (int sb = 0; sb < 16; ++sb) {
    const float* pp = ppart + ((size_t)b * 16 + sb) * D_MODEL;
    a0 += pp[t]; a1 += pp[t + 256]; a2 += pp[t + 512];
  }
  float cnt = 0.f;
  for (int s = 0; s < S_LEN; ++s) cnt += (float)att[b * S_LEN + s];
  cnt = fmaxf(cnt, 1e-9f);
  pooled[b * D_MODEL + t]       = a0 / cnt;
  pooled[b * D_MODEL + t + 256] = a1 / cnt;
  pooled[b * D_MODEL + t + 512] = a2 / cnt;
}

// ---------------------------------------------------------------------------
// head
// ---------------------------------------------------------------------------
__global__ __launch_bounds__(256) void head_kernel(
    const float* __restrict__ pooled, const float* __restrict__ Wh1,
    const float* __restrict__ bh1, const float* __restrict__ Wh2,
    const float* __restrict__ bh2, float* __restrict__ out) {
  __shared__ float hbuf[2][256];
  int t = threadIdx.x;
  for (int b = 0; b < 2; ++b) {
    float acc = bh1[t];
    for (int d = 0; d < D_MODEL; ++d) acc += pooled[b * D_MODEL + d] * Wh1[d * 256 + t];
    hbuf[b][t] = fmaxf(acc, 0.f);
  }
  __syncthreads();
  if (t < 28) {
    int b = t / 14, j = t % 14;
    float acc = bh2[j];
    for (int i = 0; i < 256; ++i) acc += hbuf[b][i] * Wh2[i * 14 + j];
    out[t] = 4.f / (1.f + __expf(-acc));
  }
}

extern "C" void kernel_launch(void* const* d_in, const int* in_sizes, int n_in,
                              void* d_out, int out_size, void* d_ws,
                              size_t ws_size, hipStream_t stream) {
  const int* ids    = (const int*)d_in[0];
  const int* att    = (const int*)d_in[1];
  const float* wemb = (const float*)d_in[2];
  const float* pemb = (const float*)d_in[3];
  const float* elng = (const float*)d_in[4];
  const float* elnb = (const float*)d_in[5];
  const float* Wq   = (const float*)d_in[6];
  const float* bq   = (const float*)d_in[7];
  const float* Wk   = (const float*)d_in[8];
  const float* bk   = (const float*)d_in[9];
  const float* Wv   = (const float*)d_in[10];
  const float* bv   = (const float*)d_in[11];
  const float* Wo   = (const float*)d_in[12];
  const float* bo   = (const float*)d_in[13];
  const float* ln1g = (const float*)d_in[14];
  const float* ln1b = (const float*)d_in[15];
  const float* Wf1  = (const float*)d_in[16];
  const float* bf1  = (const float*)d_in[17];
  const float* Wf2  = (const float*)d_in[18];
  const float* bf2  = (const float*)d_in[19];
  const float* ln2g = (const float*)d_in[20];
  const float* ln2b = (const float*)d_in[21];
  const float* Wh1  = (const float*)d_in[22];
  const float* bh1  = (const float*)d_in[23];
  const float* Wh2  = (const float*)d_in[24];
  const float* bh2  = (const float*)d_in[25];

  const int M = BATCH * S_LEN;  // 8192
  float* ws = (float*)d_ws;
  float* X  = ws;
  float* T  = ws + 6291456;
  unsigned short* QKV = (unsigned short*)(ws + 12582912);
  unsigned short* Vt  = (unsigned short*)(ws + 22020096);
  unsigned short* FFbf = QKV;
  unsigned short* Abbf = (unsigned short*)(ws + 23592960);
  unsigned short* Xbf  = (unsigned short*)(ws + 26738688);
  unsigned short* Wbf  = (unsigned short*)(ws + 29884416);
  float* pooled = ws + 36962304;
  float* ppart  = ws + 36963840;

  wconv_kernel<<<13824, 256, 0, stream>>>(Wq, Wk, Wv, Wo, Wf1, Wf2, Wbf);
  embed_ln_kernel<<<M, 256, 0, stream>>>(ids, wemb, pemb, elng, elnb, X, Xbf);

  for (int l = 0; l < NLAYER; ++l) {
    const unsigned short* wqkv = Wbf + (size_t)l * 7077888;
    const unsigned short* wot  = wqkv + 1769472;
    const unsigned short* wf1t = wqkv + 2359296;
    const unsigned short* wf2t = wqkv + 4718592;

    // fused QKV: 256^2 8-phase, grid (2304/256, 8192/256) = (9,32)
    gemm8p<4><<<dim3(9, 32), 512, 0, stream>>>(
        Xbf, wqkv, bq + l * D_MODEL, bk + l * D_MODEL, bv + l * D_MODEL,
        QKV, M, QSTR, 768);

    vtrans_kernel<<<dim3(64, NHEAD, BATCH), 256, 0, stream>>>(QKV + 1536, Vt);
    band_attn_kernel<<<dim3(17, NHEAD, BATCH), 512, 0, stream>>>(
        QKV, QKV + 768, QKV + 1536, Vt, att, Abbf);

    gemm_bf16<2><<<dim3(6, 64), 256, 0, stream>>>(
        Abbf, wot, bo + l * D_MODEL, X, T, M, 768, 768);
    ln_kernel<<<M, 256, 0, stream>>>(T, ln1g + l * D_MODEL, ln1b + l * D_MODEL, X, Xbf);

    // FFN1: 256^2 8-phase, grid (3072/256, 8192/256) = (12,32)
    gemm8p<1><<<dim3(12, 32), 512, 0, stream>>>(
        Xbf, wf1t, bf1 + l * DFF, nullptr, nullptr, FFbf, M, DFF, 768);
    gemm_bf16<2><<<dim3(6, 64), 256, 0, stream>>>(
        FFbf, wf2t, bf2 + l * D_MODEL, X, T, M, 768, DFF);
    ln_kernel<<<M, 256, 0, stream>>>(T, ln2g + l * D_MODEL, ln2b + l * D_MODEL, X, Xbf);
  }

  pool1_kernel<<<dim3(16, BATCH), 256, 0, stream>>>(X, att, ppart);
  pool2_kernel<<<BATCH, 256, 0, stream>>>(ppart, att, pooled);
  head_kernel<<<1, 256, 0, stream>>>(pooled, Wh1, bh1, Wh2, bh2, (float*)d_out);
}

// Round 7
// 830.793 us; speedup vs baseline: 1.0904x; 1.0904x over previous
//
#include <hip/hip_runtime.h>
#include <hip/hip_bf16.h>
#include <math.h>

#define S_LEN 4096
#define D_MODEL 768
#define NHEAD 12
#define DH 64
#define NLAYER 2
#define DFF 3072
#define BATCH 2
#define QSTR 2304   // fused QKV row stride

typedef __attribute__((ext_vector_type(8))) __bf16 bf16x8;
typedef __attribute__((ext_vector_type(4))) float f32x4;
typedef __attribute__((ext_vector_type(16))) float f32x16;

__device__ __forceinline__ unsigned short f2bf_bits(float f) {
  unsigned int u = __float_as_uint(f);
  unsigned int r = (u + 0x7fffu + ((u >> 16) & 1u)) >> 16;
  return (unsigned short)r;
}

__device__ __forceinline__ float bf2f(unsigned short u) {
  return __uint_as_float(((unsigned int)u) << 16);
}

__device__ __forceinline__ unsigned int cvtpk_bf16(float lo, float hi) {
  unsigned int d;
  asm("v_cvt_pk_bf16_f32 %0, %1, %2" : "=v"(d) : "v"(lo), "v"(hi));
  return d;
}

// tanh-gelu with cheap tanh via one __expf (clamped)
__device__ __forceinline__ float gelu_fast(float x) {
  float u = 0.7978845608028654f * (x + 0.044715f * x * x * x);
  float t2 = fminf(fmaxf(2.f * u, -18.f), 18.f);
  float e = __expf(t2);
  return 0.5f * x * (1.f + (e - 1.f) / (e + 1.f));
}

#define ASYNC_COPY16(gsrc, ldst)                                       \
  __builtin_amdgcn_global_load_lds(                                    \
      (const __attribute__((address_space(1))) void*)(gsrc),           \
      (__attribute__((address_space(3))) void*)(ldst), 16, 0, 0)

#define MFMA_BF16(a, b, c) __builtin_amdgcn_mfma_f32_16x16x32_bf16(a, b, c, 0, 0, 0)
#define MFMA32_BF16(a, b, c) __builtin_amdgcn_mfma_f32_32x32x16_bf16(a, b, c, 0, 0, 0)

// ---------------------------------------------------------------------------
__device__ __forceinline__ float blk_sum256(float v, float* lds) {
#pragma unroll
  for (int off = 32; off > 0; off >>= 1) v += __shfl_down(v, off, 64);
  __syncthreads();
  if ((threadIdx.x & 63) == 0) lds[threadIdx.x >> 6] = v;
  __syncthreads();
  return lds[0] + lds[1] + lds[2] + lds[3];
}

// ---------------------------------------------------------------------------
// weight transpose + fp32->bf16 convert: W[K][N] f32 -> Wt[N][K] bf16
// ---------------------------------------------------------------------------
__global__ __launch_bounds__(256) void wconv_kernel(
    const float* __restrict__ Wq, const float* __restrict__ Wk,
    const float* __restrict__ Wv, const float* __restrict__ Wo,
    const float* __restrict__ Wf1, const float* __restrict__ Wf2,
    unsigned short* __restrict__ Wbf) {
  int id = blockIdx.x;
  const float* src;
  unsigned short* dst;
  int K, N, t;
  if (id < 4608) {
    int m = id / 576;
    t = id % 576;
    int layer = m >> 2, which = m & 3;
    const float* s = (which == 0) ? Wq : (which == 1) ? Wk : (which == 2) ? Wv : Wo;
    src = s + (size_t)layer * 589824;
    dst = Wbf + (size_t)layer * 7077888 + (size_t)which * 589824;
    K = 768; N = 768;
  } else if (id < 9216) {
    int j = id - 4608;
    int layer = j / 2304;
    t = j % 2304;
    src = Wf1 + (size_t)layer * 2359296;
    dst = Wbf + (size_t)layer * 7077888 + 2359296;
    K = 768; N = 3072;
  } else {
    int j = id - 9216;
    int layer = j / 2304;
    t = j % 2304;
    src = Wf2 + (size_t)layer * 2359296;
    dst = Wbf + (size_t)layer * 7077888 + 4718592;
    K = 3072; N = 768;
  }
  int tiles_n = N >> 5;
  int tk = t / tiles_n, tn = t % tiles_n;
  __shared__ float tile[32][33];
  int c = threadIdx.x & 31, r0 = threadIdx.x >> 5;
#pragma unroll
  for (int p = 0; p < 4; ++p) {
    int r = r0 + p * 8;
    tile[r][c] = src[(size_t)(tk * 32 + r) * N + tn * 32 + c];
  }
  __syncthreads();
#pragma unroll
  for (int p = 0; p < 4; ++p) {
    int r = r0 + p * 8;
    dst[(size_t)(tn * 32 + r) * K + tk * 32 + c] = f2bf_bits(tile[c][r]);
  }
}

// ---------------------------------------------------------------------------
// embedding gather + LayerNorm -> bf16 Xb only
// ---------------------------------------------------------------------------
__global__ __launch_bounds__(256) void embed_ln_kernel(
    const int* __restrict__ ids, const float* __restrict__ wemb,
    const float* __restrict__ pemb, const float* __restrict__ g,
    const float* __restrict__ b, unsigned short* __restrict__ Xb) {
  int row = blockIdx.x;
  int s = row % S_LEN;
  int id = ids[row];
  const float* we = wemb + (size_t)id * D_MODEL;
  const float* pe = pemb + (size_t)s * D_MODEL;
  int t = threadIdx.x;
  __shared__ float lds[4];
  float v0 = we[t] + pe[t];
  float v1 = we[t + 256] + pe[t + 256];
  float v2 = we[t + 512] + pe[t + 512];
  float mean = blk_sum256(v0 + v1 + v2, lds) * (1.f / 768.f);
  float d0 = v0 - mean, d1 = v1 - mean, d2 = v2 - mean;
  float var = blk_sum256(d0 * d0 + d1 * d1 + d2 * d2, lds) * (1.f / 768.f);
  float rs = rsqrtf(var + 1e-5f);
  unsigned short* xb = Xb + (size_t)row * D_MODEL;
  xb[t]       = f2bf_bits(d0 * rs * g[t] + b[t]);
  xb[t + 256] = f2bf_bits(d1 * rs * g[t + 256] + b[t + 256]);
  xb[t + 512] = f2bf_bits(d2 * rs * g[t + 512] + b[t + 512]);
}

// ---------------------------------------------------------------------------
// LayerNorm: Xb = LN(T) * g + b  (T f32 in, bf16 out only)
// ---------------------------------------------------------------------------
__global__ __launch_bounds__(256) void ln_kernel(
    const float* __restrict__ T, const float* __restrict__ g,
    const float* __restrict__ b, unsigned short* __restrict__ Xb) {
  int row = blockIdx.x;
  const float* tp = T + (size_t)row * D_MODEL;
  int t = threadIdx.x;
  __shared__ float lds[4];
  float v0 = tp[t], v1 = tp[t + 256], v2 = tp[t + 512];
  float mean = blk_sum256(v0 + v1 + v2, lds) * (1.f / 768.f);
  float d0 = v0 - mean, d1 = v1 - mean, d2 = v2 - mean;
  float var = blk_sum256(d0 * d0 + d1 * d1 + d2 * d2, lds) * (1.f / 768.f);
  float rs = rsqrtf(var + 1e-5f);
  unsigned short* xb = Xb + (size_t)row * D_MODEL;
  xb[t]       = f2bf_bits(d0 * rs * g[t] + b[t]);
  xb[t + 256] = f2bf_bits(d1 * rs * g[t + 256] + b[t + 256]);
  xb[t + 512] = f2bf_bits(d2 * rs * g[t + 512] + b[t + 512]);
}

// ---------------------------------------------------------------------------
// 32x32x16-MFMA GEMM: 128x128 tile, BK=32, 4 waves (2x2), 3-buf counted
// vmcnt pipeline (r5 skeleton). Per wave: 2x2 of 32x32 tiles, acc f32x16.
// A/B frag: row = lane&31, k = (lane>>5)*8 within 16-k sub-step.
// C/D: col = lane&31, row = (reg&3) + 8*(reg>>2) + 4*(lane>>5)  [m74/m101].
// LDS chunk XOR key: (row>>1)&3 (both staging source and reads).
// MODE 1: out bf16, +bias0, gelu           (FFN1)
// MODE 2: out f32, +bias0, +Res bf16       (O-proj / FFN2), N must be 768
// MODE 4: out bf16 stride N, 3 biases, cols<768 scaled 1/8 (QKV)
// ---------------------------------------------------------------------------
template <int MODE>
__global__ __launch_bounds__(256) void gemm32(
    const unsigned short* __restrict__ A, const unsigned short* __restrict__ Bt,
    const float* __restrict__ bias0, const float* __restrict__ bias1,
    const float* __restrict__ bias2, const unsigned short* __restrict__ ResBf,
    void* __restrict__ Cout, int M, int N, int K) {
  __shared__ unsigned short Abuf[3][128 * 32];
  __shared__ unsigned short Bbuf[3][128 * 32];
  const int tid = threadIdx.x;
  const int lane = tid & 63, w = tid >> 6;
  const int wm = w >> 1, wn = w & 1;
  const int l31 = lane & 31, l5 = lane >> 5;

  const int nbx = gridDim.x;
  const int nwg = nbx * gridDim.y;
  const int orig = blockIdx.y * nbx + blockIdx.x;
  const int wgid = (orig & 7) * (nwg >> 3) + (orig >> 3);
  const int m0 = (wgid / nbx) * 128, n0 = (wgid % nbx) * 128;

  f32x16 acc[2][2];
#pragma unroll
  for (int i = 0; i < 2; ++i)
#pragma unroll
    for (int j = 0; j < 2; ++j)
#pragma unroll
      for (int r = 0; r < 16; ++r) acc[i][j][r] = 0.f;

  // staging: slot s -> row r=s>>2, LDS chunk s&3 (linear); source chunk
  // permuted with key (r>>1)&3.
  const int s0 = w * 64 + lane, s1 = s0 + 256;
  const int r0 = s0 >> 2, c0 = (s0 & 3) ^ ((r0 >> 1) & 3);
  const int r1 = s1 >> 2, c1 = (s1 & 3) ^ ((r1 >> 1) & 3);
  const unsigned short* gA0 = A + (size_t)(m0 + r0) * K + c0 * 8;
  const unsigned short* gA1 = A + (size_t)(m0 + r1) * K + c1 * 8;
  const unsigned short* gB0 = Bt + (size_t)(n0 + r0) * K + c0 * 8;
  const unsigned short* gB1 = Bt + (size_t)(n0 + r1) * K + c1 * 8;
  const int dA0 = (w * 64) * 8, dA1 = (256 + w * 64) * 8;

  // fragment read offsets: [mt or nt][ksub]
  int aoff[2][2], boff[2][2];
#pragma unroll
  for (int mt = 0; mt < 2; ++mt) {
    int ra = wm * 64 + mt * 32 + l31;
    int rb = wn * 64 + mt * 32 + l31;
    int key_a = (ra >> 1) & 3, key_b = (rb >> 1) & 3;
#pragma unroll
    for (int ks = 0; ks < 2; ++ks) {
      aoff[mt][ks] = ra * 32 + ((((ks << 1) | l5) ^ key_a) << 3);
      boff[mt][ks] = rb * 32 + ((((ks << 1) | l5) ^ key_b) << 3);
    }
  }

#define STAGE(bsel)                                                       \
  {                                                                       \
    ASYNC_COPY16(gA0, &Abuf[bsel][dA0]);                                  \
    ASYNC_COPY16(gA1, &Abuf[bsel][dA1]);                                  \
    ASYNC_COPY16(gB0, &Bbuf[bsel][dA0]);                                  \
    ASYNC_COPY16(gB1, &Bbuf[bsel][dA1]);                                  \
    gA0 += 32; gA1 += 32; gB0 += 32; gB1 += 32;                           \
  }

  const int nk = K >> 5;
  STAGE(0);
  if (nk > 1) STAGE(1);
  asm volatile("s_waitcnt vmcnt(4)" ::: "memory");
  __builtin_amdgcn_s_barrier();
  __builtin_amdgcn_sched_barrier(0);

  int cur = 0;
  for (int kt = 0; kt < nk; ++kt) {
    if (kt + 2 < nk) {
      int nxt = cur + 2;
      if (nxt >= 3) nxt -= 3;
      STAGE(nxt);
    }
    bf16x8 av[2][2], bv[2][2];
#pragma unroll
    for (int mt = 0; mt < 2; ++mt)
#pragma unroll
      for (int ks = 0; ks < 2; ++ks) {
        av[mt][ks] = *(const bf16x8*)(&Abuf[cur][aoff[mt][ks]]);
        bv[mt][ks] = *(const bf16x8*)(&Bbuf[cur][boff[mt][ks]]);
      }
#pragma unroll
    for (int mt = 0; mt < 2; ++mt)
#pragma unroll
      for (int nt = 0; nt < 2; ++nt)
#pragma unroll
        for (int ks = 0; ks < 2; ++ks)
          acc[mt][nt] = MFMA32_BF16(av[mt][ks], bv[nt][ks], acc[mt][nt]);
    if (kt + 1 < nk) {
      if (kt + 2 < nk)
        asm volatile("s_waitcnt vmcnt(4)" ::: "memory");
      else
        asm volatile("s_waitcnt vmcnt(0)" ::: "memory");
      __builtin_amdgcn_s_barrier();
      __builtin_amdgcn_sched_barrier(0);
    }
    cur = (cur == 2) ? 0 : cur + 1;
  }
#undef STAGE

  // epilogue: row = (reg&3) + 8*(reg>>2) + 4*l5, col = l31
#pragma unroll
  for (int mt = 0; mt < 2; ++mt) {
#pragma unroll
    for (int nt = 0; nt < 2; ++nt) {
      int gc = n0 + wn * 64 + nt * 32 + l31;
      float bsv;
      if (MODE == 4)
        bsv = (gc < 768) ? bias0[gc] : (gc < 1536) ? bias1[gc - 768] : bias2[gc - 1536];
      else
        bsv = bias0[gc];
#pragma unroll
      for (int reg = 0; reg < 16; ++reg) {
        int gr = m0 + wm * 64 + mt * 32 + (reg & 3) + 8 * (reg >> 2) + 4 * l5;
        float v = acc[mt][nt][reg] + bsv;
        if (MODE == 1) v = gelu_fast(v);
        if (MODE == 4 && gc < 768) v *= 0.125f;
        if (MODE == 2) {
          v += bf2f(ResBf[(size_t)gr * 768 + gc]);
          ((float*)Cout)[(size_t)gr * N + gc] = v;
        } else {
          ((unsigned short*)Cout)[(size_t)gr * N + gc] = f2bf_bits(v);
        }
      }
    }
  }
}

// ---------------------------------------------------------------------------
// CONTROL (A/B): r5's 16x16x32 GEMM, MODE 1 only (FFN1 layer 0)
// ---------------------------------------------------------------------------
__global__ __launch_bounds__(256) void gemm_bf16_m1(
    const unsigned short* __restrict__ A, const unsigned short* __restrict__ Bt,
    const float* __restrict__ bias0, unsigned short* __restrict__ Cout,
    int M, int N, int K) {
  __shared__ unsigned short Abuf[3][128 * 32];
  __shared__ unsigned short Bbuf[3][128 * 32];
  const int tid = threadIdx.x;
  const int lane = tid & 63, w = tid >> 6;
  const int wm = w >> 1, wn = w & 1;

  const int nbx = gridDim.x;
  const int nwg = nbx * gridDim.y;
  const int orig = blockIdx.y * nbx + blockIdx.x;
  const int wgid = (orig & 7) * (nwg >> 3) + (orig >> 3);
  const int m0 = (wgid / nbx) * 128, n0 = (wgid % nbx) * 128;

  f32x4 acc[4][4];
#pragma unroll
  for (int i = 0; i < 4; ++i)
#pragma unroll
    for (int j = 0; j < 4; ++j) acc[i][j] = (f32x4){0.f, 0.f, 0.f, 0.f};

  const int s0 = w * 64 + lane, s1 = s0 + 256;
  const int r0 = s0 >> 2, c0 = (s0 & 3) ^ (r0 & 3);
  const int r1 = s1 >> 2, c1 = (s1 & 3) ^ (r1 & 3);
  const unsigned short* gA0 = A + (size_t)(m0 + r0) * K + c0 * 8;
  const unsigned short* gA1 = A + (size_t)(m0 + r1) * K + c1 * 8;
  const unsigned short* gB0 = Bt + (size_t)(n0 + r0) * K + c0 * 8;
  const unsigned short* gB1 = Bt + (size_t)(n0 + r1) * K + c1 * 8;
  const int dA0 = (w * 64) * 8, dA1 = (256 + w * 64) * 8;

  const int frow = lane & 15, kgrp = lane >> 4;
  int aoff[4], boff[4];
#pragma unroll
  for (int i = 0; i < 4; ++i) {
    int ra = wm * 64 + i * 16 + frow;
    int rb = wn * 64 + i * 16 + frow;
    aoff[i] = ra * 32 + ((kgrp ^ (ra & 3)) * 8);
    boff[i] = rb * 32 + ((kgrp ^ (rb & 3)) * 8);
  }

#define STAGE(bsel)                                                       \
  {                                                                       \
    ASYNC_COPY16(gA0, &Abuf[bsel][dA0]);                                  \
    ASYNC_COPY16(gA1, &Abuf[bsel][dA1]);                                  \
    ASYNC_COPY16(gB0, &Bbuf[bsel][dA0]);                                  \
    ASYNC_COPY16(gB1, &Bbuf[bsel][dA1]);                                  \
    gA0 += 32; gA1 += 32; gB0 += 32; gB1 += 32;                           \
  }

  const int nk = K >> 5;
  STAGE(0);
  if (nk > 1) STAGE(1);
  asm volatile("s_waitcnt vmcnt(4)" ::: "memory");
  __builtin_amdgcn_s_barrier();
  __builtin_amdgcn_sched_barrier(0);

  int cur = 0;
  for (int kt = 0; kt < nk; ++kt) {
    if (kt + 2 < nk) {
      int nxt = cur + 2;
      if (nxt >= 3) nxt -= 3;
      STAGE(nxt);
    }
    bf16x8 av[4], bv[4];
#pragma unroll
    for (int i = 0; i < 4; ++i) av[i] = *(const bf16x8*)(&Abuf[cur][aoff[i]]);
#pragma unroll
    for (int j = 0; j < 4; ++j) bv[j] = *(const bf16x8*)(&Bbuf[cur][boff[j]]);
#pragma unroll
    for (int i = 0; i < 4; ++i)
#pragma unroll
      for (int j = 0; j < 4; ++j)
        acc[i][j] = MFMA_BF16(av[i], bv[j], acc[i][j]);
    if (kt + 1 < nk) {
      if (kt + 2 < nk)
        asm volatile("s_waitcnt vmcnt(4)" ::: "memory");
      else
        asm volatile("s_waitcnt vmcnt(0)" ::: "memory");
      __builtin_amdgcn_s_barrier();
      __builtin_amdgcn_sched_barrier(0);
    }
    cur = (cur == 2) ? 0 : cur + 1;
  }
#undef STAGE

#pragma unroll
  for (int i = 0; i < 4; ++i) {
#pragma unroll
    for (int j = 0; j < 4; ++j) {
      int grb = m0 + wm * 64 + i * 16 + (lane >> 4) * 4;
      int gc = n0 + wn * 64 + j * 16 + (lane & 15);
      float bsv = bias0[gc];
#pragma unroll
      for (int r = 0; r < 4; ++r) {
        float v = gelu_fast(acc[i][j][r] + bsv);
        Cout[(size_t)(grb + r) * N + gc] = f2bf_bits(v);
      }
    }
  }
}

// ---------------------------------------------------------------------------
// V transpose per (b,h): QKV V-cols -> Vt[(b*12+h)*64 + d][4096] bf16
// ---------------------------------------------------------------------------
__global__ __launch_bounds__(256) void vtrans_kernel(
    const unsigned short* __restrict__ Vsrc, unsigned short* __restrict__ Vt) {
  int kb = blockIdx.x, h = blockIdx.y, b = blockIdx.z;
  int k0 = kb * 64;
  const size_t bs = (size_t)b * S_LEN;
  const size_t bh = (size_t)(b * NHEAD + h);
  __shared__ unsigned short tile[64][72];
  int tid = threadIdx.x;
#pragma unroll
  for (int p = 0; p < 2; ++p) {
    int idx = p * 256 + tid;
    int key = idx >> 3, ch = idx & 7;
    bf16x8 v = *(const bf16x8*)(Vsrc + (bs + k0 + key) * QSTR + h * DH + ch * 8);
    *(bf16x8*)&tile[key][ch * 8] = v;
  }
  __syncthreads();
#pragma unroll
  for (int p = 0; p < 2; ++p) {
    int idx = p * 256 + tid;
    int d = idx >> 3, kc = idx & 7;
    unsigned int w0 = tile[kc * 8 + 0][d] | ((unsigned int)tile[kc * 8 + 1][d] << 16);
    unsigned int w1 = tile[kc * 8 + 2][d] | ((unsigned int)tile[kc * 8 + 3][d] << 16);
    unsigned int w2 = tile[kc * 8 + 4][d] | ((unsigned int)tile[kc * 8 + 5][d] << 16);
    unsigned int w3 = tile[kc * 8 + 6][d] | ((unsigned int)tile[kc * 8 + 7][d] << 16);
    uint4 out = make_uint4(w0, w1, w2, w3);
    *(uint4*)(Vt + (bh * 64 + d) * S_LEN + k0 + kc * 8) = out;
  }
}

// ---------------------------------------------------------------------------
// MFMA band attention + fused global-row-0 path. grid (17, 12, 2), 512 thr.
// ---------------------------------------------------------------------------
__global__ __launch_bounds__(512) void band_attn_kernel(
    const unsigned short* __restrict__ Qg, const unsigned short* __restrict__ Kgb,
    const unsigned short* __restrict__ Vgb, const unsigned short* __restrict__ Vt,
    const int* __restrict__ att, unsigned short* __restrict__ Aout) {
  const int c = blockIdx.x, h = blockIdx.y, b = blockIdx.z;
  const int tid = threadIdx.x;
  const int lane = tid & 63, wq = tid >> 6;
  const int g = lane >> 4, cl = lane & 15;
  const size_t bs = (size_t)b * S_LEN;
  const size_t bh = (size_t)(b * NHEAD + h);

  __shared__ __align__(16) char smem[18944];

  if (c == 16) {
    float* sc = (float*)smem;
    float* q0 = sc + S_LEN;
    float* red = q0 + 64;
    float* part = red + 8;
    if (tid < 64) q0[tid] = bf2f(Qg[bs * QSTR + h * DH + tid]);
    __syncthreads();
    float lmax = -1e30f;
    for (int s = tid; s < S_LEN; s += 512) {
      const unsigned short* kp = Kgb + (bs + s) * QSTR + h * DH;
      float acc = 0.f;
#pragma unroll
      for (int cc = 0; cc < 8; ++cc) {
        uint4 u = *(const uint4*)(kp + cc * 8);
        const unsigned int* uu = (const unsigned int*)&u;
#pragma unroll
        for (int w2 = 0; w2 < 4; ++w2) {
          unsigned int x = uu[w2];
          acc += q0[cc * 8 + w2 * 2] * __uint_as_float(x << 16);
          acc += q0[cc * 8 + w2 * 2 + 1] * __uint_as_float(x & 0xffff0000u);
        }
      }
      acc = (att[b * S_LEN + s] > 0) ? acc : -1e9f;
      sc[s] = acc;
      lmax = fmaxf(lmax, acc);
    }
#pragma unroll
    for (int off = 32; off > 0; off >>= 1) lmax = fmaxf(lmax, __shfl_down(lmax, off, 64));
    __syncthreads();
    if (lane == 0) red[wq] = lmax;
    __syncthreads();
    float M = red[0];
#pragma unroll
    for (int i = 1; i < 8; ++i) M = fmaxf(M, red[i]);
    float lsum = 0.f;
    for (int s = tid; s < S_LEN; s += 512) {
      float p = __expf(sc[s] - M);
      sc[s] = p;
      lsum += p;
    }
#pragma unroll
    for (int off = 32; off > 0; off >>= 1) lsum += __shfl_down(lsum, off, 64);
    __syncthreads();
    if (lane == 0) red[wq] = lsum;
    __syncthreads();
    float L = red[0];
#pragma unroll
    for (int i = 1; i < 8; ++i) L += red[i];
    int d = tid & 63, chunk = tid >> 6;
    float acc2 = 0.f;
    for (int s = chunk * 512; s < (chunk + 1) * 512; ++s)
      acc2 += sc[s] * bf2f(Vgb[(bs + s) * QSTR + h * DH + d]);
    part[chunk * 64 + d] = acc2;
    __syncthreads();
    if (tid < 64) {
      float v = 0.f;
#pragma unroll
      for (int i = 0; i < 8; ++i) v += part[i * 64 + tid];
      Aout[bs * D_MODEL + h * DH + tid] = f2bf_bits(v / L);
    }
    return;
  }

  unsigned short* Klds = (unsigned short*)smem;
  unsigned short* Vlds = Klds + 64 * 64;
  float* kmask = (float*)(Vlds + 64 * 64);

  bf16x8 qf[2][2];
#pragma unroll
  for (int qt = 0; qt < 2; ++qt)
#pragma unroll
    for (int ks = 0; ks < 2; ++ks)
      qf[qt][ks] = *(const bf16x8*)(Qg + (bs + c * 256 + wq * 32 + qt * 16 + cl) * QSTR +
                                    h * DH + ks * 32 + g * 8);

  float mrun[2], lrun[2];
  f32x4 oacc[2][4];
#pragma unroll
  for (int qt = 0; qt < 2; ++qt) {
    float sg = 0.f;
#pragma unroll
    for (int ks = 0; ks < 2; ++ks) {
      bf16x8 k0 = *(const bf16x8*)(Kgb + bs * QSTR + h * DH + ks * 32 + g * 8);
#pragma unroll
      for (int j = 0; j < 8; ++j) sg += (float)qf[qt][ks][j] * (float)k0[j];
    }
    sg += __shfl_xor(sg, 16, 64);
    sg += __shfl_xor(sg, 32, 64);
    mrun[qt] = sg;
    lrun[qt] = 1.f;
  }
#pragma unroll
  for (int dt = 0; dt < 4; ++dt) {
    float v0d = bf2f(Vgb[bs * QSTR + h * DH + dt * 16 + cl]);
    f32x4 vv = {v0d, v0d, v0d, v0d};
    oacc[0][dt] = vv;
    oacc[1][dt] = vv;
  }

  const int jlo = wq * 32, jhi = wq * 32 + 543;

  for (int t = 0; t < 12; ++t) {
    int kabs0 = c * 256 - 256 + t * 64;
    if (kabs0 < 0 || kabs0 >= S_LEN) continue;
    __syncthreads();
    {
      int key = tid >> 3, ch = tid & 7;
      bf16x8 kv = *(const bf16x8*)(Kgb + (bs + kabs0 + key) * QSTR + h * DH + ch * 8);
      *(bf16x8*)(Klds + key * 64 + ((ch ^ (key & 7)) * 8)) = kv;
      bf16x8 vv = *(const bf16x8*)(Vt + (bh * 64 + key) * S_LEN + kabs0 + ch * 8);
      *(bf16x8*)(Vlds + key * 64 + ((ch ^ (key & 7)) * 8)) = vv;
      if (tid < 64) {
        int ka = kabs0 + tid;
        kmask[tid] = (ka >= 1 && att[b * S_LEN + ka] > 0) ? 0.f : -1e9f;
      }
    }
    __syncthreads();
    if (t * 64 + 63 < jlo || t * 64 > jhi) continue;

    f32x4 accs[4][2];
#pragma unroll
    for (int kt = 0; kt < 4; ++kt) {
      accs[kt][0] = (f32x4){0.f, 0.f, 0.f, 0.f};
      accs[kt][1] = (f32x4){0.f, 0.f, 0.f, 0.f};
    }
#pragma unroll
    for (int ks = 0; ks < 2; ++ks) {
      bf16x8 kf[4];
#pragma unroll
      for (int kt = 0; kt < 4; ++kt) {
        int key = kt * 16 + cl;
        kf[kt] = *(const bf16x8*)(Klds + key * 64 + (((ks * 4 + g) ^ (key & 7)) * 8));
      }
#pragma unroll
      for (int kt = 0; kt < 4; ++kt) {
        accs[kt][0] = MFMA_BF16(kf[kt], qf[0][ks], accs[kt][0]);
        accs[kt][1] = MFMA_BF16(kf[kt], qf[1][ks], accs[kt][1]);
      }
    }

#pragma unroll
    for (int qt = 0; qt < 2; ++qt) {
      int iq = wq * 32 + qt * 16 + cl;
      int relbase = t * 64 - iq;
      float pvv[4][4];
      float tmax = -1e30f;
#pragma unroll
      for (int kt = 0; kt < 4; ++kt)
#pragma unroll
        for (int r = 0; r < 4; ++r) {
          int key = kt * 16 + g * 4 + r;
          int rel = relbase + key;
          float x = accs[kt][qt][r] + kmask[key];
          x = (rel >= 0 && rel <= 512) ? x : -1e9f;
          pvv[kt][r] = x;
          tmax = fmaxf(tmax, x);
        }
      tmax = fmaxf(tmax, __shfl_xor(tmax, 16, 64));
      tmax = fmaxf(tmax, __shfl_xor(tmax, 32, 64));
      float mnew = fmaxf(mrun[qt], tmax);
      float scale = __expf(mrun[qt] - mnew);
      mrun[qt] = mnew;
      float psum = 0.f;
#pragma unroll
      for (int kt = 0; kt < 4; ++kt)
#pragma unroll
        for (int r = 0; r < 4; ++r) {
          float p = __expf(pvv[kt][r] - mnew);
          pvv[kt][r] = p;
          psum += p;
        }
      psum += __shfl_xor(psum, 16, 64);
      psum += __shfl_xor(psum, 32, 64);
      lrun[qt] = lrun[qt] * scale + psum;
      float scr[4];
#pragma unroll
      for (int r = 0; r < 4; ++r) scr[r] = __shfl(scale, g * 4 + r, 64);
#pragma unroll
      for (int dt = 0; dt < 4; ++dt) {
        oacc[qt][dt][0] *= scr[0];
        oacc[qt][dt][1] *= scr[1];
        oacc[qt][dt][2] *= scr[2];
        oacc[qt][dt][3] *= scr[3];
      }
#pragma unroll
      for (int ks = 0; ks < 2; ++ks) {
        unsigned int E0D0 = cvtpk_bf16(pvv[ks * 2][0], pvv[ks * 2][1]);
        unsigned int E0D1 = cvtpk_bf16(pvv[ks * 2][2], pvv[ks * 2][3]);
        unsigned int E1D0 = cvtpk_bf16(pvv[ks * 2 + 1][0], pvv[ks * 2 + 1][1]);
        unsigned int E1D1 = cvtpk_bf16(pvv[ks * 2 + 1][2], pvv[ks * 2 + 1][3]);
        int src0 = ((lane >> 4) & 1) * 32 + cl;
        int src1 = src0 + 16;
        unsigned int a0 = (unsigned int)__shfl((int)E0D0, src0, 64);
        unsigned int a1 = (unsigned int)__shfl((int)E0D1, src0, 64);
        unsigned int a2 = (unsigned int)__shfl((int)E0D0, src1, 64);
        unsigned int a3 = (unsigned int)__shfl((int)E0D1, src1, 64);
        unsigned int b0 = (unsigned int)__shfl((int)E1D0, src0, 64);
        unsigned int b1 = (unsigned int)__shfl((int)E1D1, src0, 64);
        unsigned int b2 = (unsigned int)__shfl((int)E1D0, src1, 64);
        unsigned int b3 = (unsigned int)__shfl((int)E1D1, src1, 64);
        bool hi = lane >= 32;
        union { unsigned int u[4]; bf16x8 v; } af;
        af.u[0] = hi ? b0 : a0;
        af.u[1] = hi ? b1 : a1;
        af.u[2] = hi ? b2 : a2;
        af.u[3] = hi ? b3 : a3;
#pragma unroll
        for (int dt = 0; dt < 4; ++dt) {
          int d = dt * 16 + cl;
          bf16x8 vf = *(const bf16x8*)(Vlds + d * 64 + (((ks * 4 + g) ^ (d & 7)) * 8));
          oacc[qt][dt] = MFMA_BF16(af.v, vf, oacc[qt][dt]);
        }
      }
    }
  }

#pragma unroll
  for (int qt = 0; qt < 2; ++qt) {
    float lr[4];
#pragma unroll
    for (int r = 0; r < 4; ++r) lr[r] = 1.f / __shfl(lrun[qt], g * 4 + r, 64);
#pragma unroll
    for (int dt = 0; dt < 4; ++dt)
#pragma unroll
      for (int r = 0; r < 4; ++r) {
        int row = c * 256 + wq * 32 + qt * 16 + g * 4 + r;
        if (row != 0)
          Aout[(bs + row) * D_MODEL + h * DH + dt * 16 + cl] =
              f2bf_bits(oacc[qt][dt][r] * lr[r]);
      }
  }
}

// ---------------------------------------------------------------------------
// masked mean-pool over bf16 X, two stages
// ---------------------------------------------------------------------------
__global__ __launch_bounds__(256) void pool1_kernel(
    const unsigned short* __restrict__ Xb, const int* __restrict__ att,
    float* __restrict__ ppart) {
  int sb = blockIdx.x, b = blockIdx.y, t = threadIdx.x;
  float a0 = 0.f, a1 = 0.f, a2 = 0.f;
  for (int s = sb * 256; s < sb * 256 + 256; ++s) {
    float a = (float)att[b * S_LEN + s];
    const unsigned short* xp = Xb + ((size_t)b * S_LEN + s) * D_MODEL;
    a0 += bf2f(xp[t]) * a; a1 += bf2f(xp[t + 256]) * a; a2 += bf2f(xp[t + 512]) * a;
  }
  float* pp = ppart + ((size_t)b * 16 + sb) * D_MODEL;
  pp[t] = a0; pp[t + 256] = a1; pp[t + 512] = a2;
}

__global__ __launch_bounds__(256) void pool2_kernel(
    const float* __restrict__ ppart, const int* __restrict__ att,
    float* __restrict__ pooled) {
  int b = blockIdx.x, t = threadIdx.x;
  float a0 = 0.f, a1 = 0.f, a2 = 0.f;
  for (int sb = 0; sb < 16; ++sb) {
    const float* pp = ppart + ((size_t)b * 16 + sb) * D_MODEL;
    a0 += pp[t]; a1 += pp[t + 256]; a2 += pp[t + 512];
  }
  float cnt = 0.f;
  for (int s = 0; s < S_LEN; ++s) cnt += (float)att[b * S_LEN + s];
  cnt = fmaxf(cnt, 1e-9f);
  pooled[b * D_MODEL + t]       = a0 / cnt;
  pooled[b * D_MODEL + t + 256] = a1 / cnt;
  pooled[b * D_MODEL + t + 512] = a2 / cnt;
}

// ---------------------------------------------------------------------------
__global__ __launch_bounds__(256) void head_kernel(
    const float* __restrict__ pooled, const float* __restrict__ Wh1,
    const float* __restrict__ bh1, const float* __restrict__ Wh2,
    const float* __restrict__ bh2, float* __restrict__ out) {
  __shared__ float hbuf[2][256];
  int t = threadIdx.x;
  for (int b = 0; b < 2; ++b) {
    float acc = bh1[t];
    for (int d = 0; d < D_MODEL; ++d) acc += pooled[b * D_MODEL + d] * Wh1[d * 256 + t];
    hbuf[b][t] = fmaxf(acc, 0.f);
  }
  __syncthreads();
  if (t < 28) {
    int b = t / 14, j = t % 14;
    float acc = bh2[j];
    for (int i = 0; i < 256; ++i) acc += hbuf[b][i] * Wh2[i * 14 + j];
    out[t] = 4.f / (1.f + __expf(-acc));
  }
}

extern "C" void kernel_launch(void* const* d_in, const int* in_sizes, int n_in,
                              void* d_out, int out_size, void* d_ws,
                              size_t ws_size, hipStream_t stream) {
  const int* ids    = (const int*)d_in[0];
  const int* att    = (const int*)d_in[1];
  const float* wemb = (const float*)d_in[2];
  const float* pemb = (const float*)d_in[3];
  const float* elng = (const float*)d_in[4];
  const float* elnb = (const float*)d_in[5];
  const float* Wq   = (const float*)d_in[6];
  const float* bq   = (const float*)d_in[7];
  const float* Wk   = (const float*)d_in[8];
  const float* bk   = (const float*)d_in[9];
  const float* Wv   = (const float*)d_in[10];
  const float* bv   = (const float*)d_in[11];
  const float* Wo   = (const float*)d_in[12];
  const float* bo   = (const float*)d_in[13];
  const float* ln1g = (const float*)d_in[14];
  const float* ln1b = (const float*)d_in[15];
  const float* Wf1  = (const float*)d_in[16];
  const float* bf1  = (const float*)d_in[17];
  const float* Wf2  = (const float*)d_in[18];
  const float* bf2  = (const float*)d_in[19];
  const float* ln2g = (const float*)d_in[20];
  const float* ln2b = (const float*)d_in[21];
  const float* Wh1  = (const float*)d_in[22];
  const float* bh1  = (const float*)d_in[23];
  const float* Wh2  = (const float*)d_in[24];
  const float* bh2  = (const float*)d_in[25];

  const int M = BATCH * S_LEN;  // 8192
  float* ws = (float*)d_ws;
  float* T = ws;                                            // f32 [0, 6291456)
  unsigned short* QKV  = (unsigned short*)(ws + 6291456);   // 9.44M sh
  unsigned short* Vt   = (unsigned short*)(ws + 11010048);  // 3.15M sh
  unsigned short* Abbf = (unsigned short*)(ws + 12582912);  // 6.29M sh
  unsigned short* Xbf  = (unsigned short*)(ws + 15728640);  // 6.29M sh
  unsigned short* FFbf = (unsigned short*)(ws + 18874368);  // 25.17M sh
  unsigned short* Wbf  = (unsigned short*)(ws + 31457280);  // 14.16M sh
  float* pooled = ws + 38535168;
  float* ppart  = ws + 38536704;

  wconv_kernel<<<13824, 256, 0, stream>>>(Wq, Wk, Wv, Wo, Wf1, Wf2, Wbf);
  embed_ln_kernel<<<M, 256, 0, stream>>>(ids, wemb, pemb, elng, elnb, Xbf);

  for (int l = 0; l < NLAYER; ++l) {
    const unsigned short* wqkv = Wbf + (size_t)l * 7077888;
    const unsigned short* wot  = wqkv + 1769472;
    const unsigned short* wf1t = wqkv + 2359296;
    const unsigned short* wf2t = wqkv + 4718592;

    gemm32<4><<<dim3(18, 64), 256, 0, stream>>>(
        Xbf, wqkv, bq + l * D_MODEL, bk + l * D_MODEL, bv + l * D_MODEL,
        nullptr, QKV, M, QSTR, 768);

    vtrans_kernel<<<dim3(64, NHEAD, BATCH), 256, 0, stream>>>(QKV + 1536, Vt);
    band_attn_kernel<<<dim3(17, NHEAD, BATCH), 512, 0, stream>>>(
        QKV, QKV + 768, QKV + 1536, Vt, att, Abbf);

    gemm32<2><<<dim3(6, 64), 256, 0, stream>>>(
        Abbf, wot, bo + l * D_MODEL, nullptr, nullptr, Xbf, T, M, 768, 768);
    ln_kernel<<<M, 256, 0, stream>>>(T, ln1g + l * D_MODEL, ln1b + l * D_MODEL, Xbf);

    // FFN1 A/B: layer 0 = 16x16 control, layer 1 = 32x32 variant
    if (l == 0)
      gemm_bf16_m1<<<dim3(24, 64), 256, 0, stream>>>(
          Xbf, wf1t, bf1 + l * DFF, FFbf, M, DFF, 768);
    else
      gemm32<1><<<dim3(24, 64), 256, 0, stream>>>(
          Xbf, wf1t, bf1 + l * DFF, nullptr, nullptr, nullptr, FFbf, M, DFF, 768);

    gemm32<2><<<dim3(6, 64), 256, 0, stream>>>(
        FFbf, wf2t, bf2 + l * D_MODEL, nullptr, nullptr, Xbf, T, M, 768, DFF);
    ln_kernel<<<M, 256, 0, stream>>>(T, ln2g + l * D_MODEL, ln2b + l * D_MODEL, Xbf);
  }

  pool1_kernel<<<dim3(16, BATCH), 256, 0, stream>>>(Xbf, att, ppart);
  pool2_kernel<<<BATCH, 256, 0, stream>>>(ppart, att, pooled);
  head_kernel<<<1, 256, 0, stream>>>(pooled, Wh1, bh1, Wh2, bh2, (float*)d_out);
}